// Round 14
// baseline (127.348 us; speedup 1.0000x reference)
//
#include <hip/hip_runtime.h>
#include <hip/hip_bf16.h>
#include <stdint.h>

// Problem constants (from reference)
#define N1 8
#define N2 8
#define PP 1024
#define DD 768
#define PH 32
#define PW 32
#define OH 512
#define OW 512

#define NKT 12   // K tiles of 64
#define NNT 4    // column tiles of 256 (nt loop)
#define NIT (NKT * NNT)

typedef int i32x4 __attribute__((ext_vector_type(4)));

// ---------------- K1: row L2-normalize f32 -> i8 (q = round(127*x/||x||)) --
// Verified R7-R12: final absmax 3.9e-3 vs threshold 1.35e-2.
__global__ __launch_bounds__(256) void nrm_kernel(
    const float* __restrict__ inA, const float* __restrict__ inB,
    char* __restrict__ outA, char* __restrict__ outB) {
  int row = blockIdx.x;
  const float* src;
  char* dst;
  if (row < N1 * PP) {
    src = inA + (size_t)row * DD;
    dst = outA + (size_t)row * DD;
  } else {
    row -= N1 * PP;
    src = inB + (size_t)row * DD;
    dst = outB + (size_t)row * DD;
  }
  const int t = threadIdx.x;
  const float v0 = src[t], v1 = src[t + 256], v2 = src[t + 512];
  float s = v0 * v0 + v1 * v1 + v2 * v2;
#pragma unroll
  for (int m = 32; m; m >>= 1) s += __shfl_xor(s, m, 64);
  __shared__ float red[4];
  const int wave = t >> 6, lane = t & 63;
  if (lane == 0) red[wave] = s;
  __syncthreads();
  const float inv = 127.0f / sqrtf(red[0] + red[1] + red[2] + red[3]);
  dst[t]       = (char)__float2int_rn(v0 * inv);
  dst[t + 256] = (char)__float2int_rn(v1 * inv);
  dst[t + 512] = (char)__float2int_rn(v2 * inv);
}

__device__ __forceinline__ void gll16(const char* src, char* dst) {
  __builtin_amdgcn_global_load_lds(
      (const __attribute__((address_space(1))) void*)src,
      (__attribute__((address_space(3))) void*)dst, 16, 0, 0);
}

// -------- K2: i8 gram row-max, ROW-BAND blocks, fragment-packed LDS --------
// R13: one block per (pair, 128-row band): 512 blocks x 512 thr (8 waves,
// 2M x 4N; per-wave C = 64x64, acc[4][4] i32x4 = 64 regs).
//  * A panel (128 x 768 i8 = 96 KB) staged into LDS ONCE, fragment-packed:
//    chunk (rowblk 0..7, kt 0..11, lane) holds the exact 16 B lane feeds to
//    mfma_i32_16x16x64_i8: A[rowblk*16 + (lane&15)][kt*64 + (lane>>4)*16].
//    Every ds_read_b128 is base + lane*16 -> contiguous 1 KB -> 2 lanes/bank
//    (free, m136). No swizzle math anywhere.
//  * B double-buffered 2 x 16 KB, fragment-packed the same way per (nt,kt):
//    chunk (colblk 0..15, lane) = B[bcol + colblk*16 + (lane&15)][...].
//  * nt-loop sweeps all 1024 columns; rowmax kept in REGISTERS (fold per
//    nt), combined across waves via LDS atomicMax at the end, ONE coalesced
//    global store per row. Zero global atomics (was 1.05M), zero memset.
//  * Drift sync: per it {stage it+1 -> 8 ds_read -> 16 MFMA -> [fold at
//    kt==11] -> vmcnt(0) -> barrier}. Slot (it+1)&1 disjoint from reads of
//    slot it&1; its previous readers drained before the it-1 barrier.
// LDS: 96 KB A + 32 KB B + 512 B rred = 128.5 KB -> 1 block/CU, 8 waves.
__global__ __launch_bounds__(512) void grami8_kernel(
    const char* __restrict__ fq, const char* __restrict__ gq,
    int* __restrict__ rowmaxI) {
  __shared__ __align__(16) char Apk[8 * 12 * 1024];   // [rowblk][kt][lane*16]
  __shared__ __align__(16) char Bpk[2][16 * 1024];    // [slot][colblk][lane*16]
  __shared__ int rred[128];

  // XCD swizzle: 512 wgs, 64 contiguous per XCD (bijective, 512%8==0).
  const int bid = blockIdx.x;
  const int wg = (bid & 7) * 64 + (bid >> 3);
  const int pair = wg >> 3;                 // 0..63
  const int mt = wg & 7;                    // 128-row band
  const int fn = pair >> 3, gm = pair & 7;
  const int brow = mt * 128;

  const int t = threadIdx.x;
  const int lane = t & 63, wave = t >> 6;
  const int lr = lane & 15, lk = lane >> 4;
  const int wr = wave >> 2, wc = wave & 3;  // 2M x 4N, per-wave 64x64

  const char* rowA = fq + ((size_t)fn * PP + brow) * DD;
  const char* rowB = gq + (size_t)gm * PP * DD;

  if (t < 128) rred[t] = (int)0x80000000;

  // ---- A prologue: 6144 chunks, 12 gll16/thread, fragment-packed ----
#pragma unroll
  for (int j = 0; j < 12; ++j) {
    const int c = t + j * 512;
    const int rowblk = c / 768;
    const int rem = c - rowblk * 768;
    const int kt = rem >> 6;
    const int ln = rem & 63;
    gll16(rowA + (size_t)(rowblk * 16 + (ln & 15)) * DD + kt * 64 + (ln >> 4) * 16,
          &Apk[c * 16]);
  }

  // ---- B stage for linear iteration it = nt*12 + kt (2 gll16/thread) ----
#define STAGE_B(it)                                                          \
  do {                                                                       \
    const int nt_ = (it) / NKT, kt_ = (it) - nt_ * NKT;                      \
    const int slot_ = (it) & 1;                                              \
    _Pragma("unroll")                                                        \
    for (int j = 0; j < 2; ++j) {                                            \
      const int c2 = t + j * 512;                                            \
      const int colblk = c2 >> 6, ln = c2 & 63;                              \
      gll16(rowB + (size_t)(nt_ * 256 + colblk * 16 + (ln & 15)) * DD +      \
                kt_ * 64 + (ln >> 4) * 16,                                   \
            &Bpk[slot_][c2 * 16]);                                           \
    }                                                                        \
  } while (0)

  i32x4 acc[4][4];
#pragma unroll
  for (int i = 0; i < 4; ++i)
#pragma unroll
    for (int j = 0; j < 4; ++j) acc[i][j] = (i32x4){0, 0, 0, 0};
  int rmax[4][4];
#pragma unroll
  for (int i = 0; i < 4; ++i)
#pragma unroll
    for (int j = 0; j < 4; ++j) rmax[i][j] = (int)0x80000000;

  STAGE_B(0);
  asm volatile("s_waitcnt vmcnt(0)" ::: "memory");
  __builtin_amdgcn_s_barrier();
  asm volatile("" ::: "memory");

#pragma unroll 1
  for (int it = 0; it < NIT; ++it) {
    const int kt = it % NKT;
    const char* Bb = &Bpk[it & 1][0];

    if (it + 1 < NIT) STAGE_B(it + 1);

    // 8 contiguous 1-KB wave reads (4 A-frags, 4 B-frags).
    i32x4 a[4], b[4];
#pragma unroll
    for (int m = 0; m < 4; ++m)
      a[m] = *(const i32x4*)(&Apk[(((wr * 4 + m) * NKT + kt) * 64 + lane) * 16]);
#pragma unroll
    for (int n = 0; n < 4; ++n)
      b[n] = *(const i32x4*)(Bb + ((wc * 4 + n) * 64 + lane) * 16);

#pragma unroll
    for (int m = 0; m < 4; ++m)
#pragma unroll
      for (int n = 0; n < 4; ++n)
        acc[m][n] = __builtin_amdgcn_mfma_i32_16x16x64_i8(a[m], b[n],
                                                          acc[m][n], 0, 0, 0);

    // End of a column tile: fold acc into register rowmax, reset acc.
    if (kt == NKT - 1) {
#pragma unroll
      for (int m = 0; m < 4; ++m) {
#pragma unroll
        for (int r = 0; r < 4; ++r) {
          const int vv = max(max(acc[m][0][r], acc[m][1][r]),
                             max(acc[m][2][r], acc[m][3][r]));
          rmax[m][r] = max(rmax[m][r], vv);
        }
#pragma unroll
        for (int n = 0; n < 4; ++n) acc[m][n] = (i32x4){0, 0, 0, 0};
      }
    }

    asm volatile("s_waitcnt vmcnt(0)" ::: "memory");
    __builtin_amdgcn_s_barrier();
    asm volatile("" ::: "memory");
  }

  // Epilogue: reduce rmax over q-lanes (lr), combine waves in LDS, store.
  // C/D layout: col = lr (q), row = lk*4 + r.
#pragma unroll
  for (int m = 0; m < 4; ++m) {
#pragma unroll
    for (int r = 0; r < 4; ++r) {
      int vv = rmax[m][r];
      vv = max(vv, __shfl_xor(vv, 1, 64));
      vv = max(vv, __shfl_xor(vv, 2, 64));
      vv = max(vv, __shfl_xor(vv, 4, 64));
      vv = max(vv, __shfl_xor(vv, 8, 64));
      if (lr == 0) {
        atomicMax(&rred[wr * 64 + m * 16 + lk * 4 + r], vv);  // LDS atomic
      }
    }
  }
  __syncthreads();
  if (t < 128) {
    rowmaxI[(size_t)pair * PP + brow + t] = rred[t];
  }
#undef STAGE_B
}

// ---------------- K3: rowmax(i32) -> dist -> scores + sp ----------------
__global__ __launch_bounds__(256) void finalize_kernel(
    const int* __restrict__ rowmaxI, float* __restrict__ sp,
    float* __restrict__ scores) {
  const int n = blockIdx.x, t = threadIdx.x;
  const int lane = t & 63, wave = t >> 6;
  __shared__ float red[4];
  __shared__ float maxd[N2];
  float spacc[4] = {0.f, 0.f, 0.f, 0.f};
  for (int m = 0; m < N2; ++m) {
    float lmax = -1e30f;
#pragma unroll
    for (int i = 0; i < 4; ++i) {
      const int p = t + i * 256;
      const float g = (float)rowmaxI[(size_t)(n * N2 + m) * PP + p] *
                      (1.0f / 16129.0f);  // 127^2
      const float d = 0.5f * sqrtf(fmaxf(0.f, 2.f - 2.f * g));
      spacc[i] += d;
      lmax = fmaxf(lmax, d);
    }
#pragma unroll
    for (int msk = 32; msk; msk >>= 1) lmax = fmaxf(lmax, __shfl_xor(lmax, msk, 64));
    if (lane == 0) red[wave] = lmax;
    __syncthreads();
    if (t == 0) maxd[m] = fmaxf(fmaxf(red[0], red[1]), fmaxf(red[2], red[3]));
    __syncthreads();
  }
  if (t == 0) {
    float s = 0.f;
    for (int m = 0; m < N2; ++m) s += maxd[m];
    scores[n] = s * (1.0f / N2);
  }
#pragma unroll
  for (int i = 0; i < 4; ++i)
    sp[(size_t)n * PP + t + i * 256] = spacc[i] * (1.0f / N2);
}

// ---------------- K4: bilinear resize 32x32 -> 512x512 ----------------
__global__ __launch_bounds__(256) void resize_kernel(
    const float* __restrict__ sp, float* __restrict__ out) {
  const int idx = blockIdx.x * 256 + threadIdx.x;
  const int ox = idx & (OW - 1);
  const int oy = (idx >> 9) & (OH - 1);
  const int n = idx >> 18;
  const float sy = (oy + 0.5f) * ((float)PH / OH) - 0.5f;
  const float sx = (ox + 0.5f) * ((float)PW / OW) - 0.5f;
  const float y0f = floorf(sy), x0f = floorf(sx);
  const float wy = sy - y0f, wx = sx - x0f;
  int y0 = (int)y0f, x0 = (int)x0f;
  int y1 = y0 + 1, x1 = x0 + 1;
  y0 = min(max(y0, 0), PH - 1);
  y1 = min(max(y1, 0), PH - 1);
  x0 = min(max(x0, 0), PW - 1);
  x1 = min(max(x1, 0), PW - 1);
  const float* s = sp + (size_t)n * PP;
  const float v00 = s[y0 * PW + x0], v01 = s[y0 * PW + x1];
  const float v10 = s[y1 * PW + x0], v11 = s[y1 * PW + x1];
  const float top = v00 * (1.f - wx) + v01 * wx;
  const float bot = v10 * (1.f - wx) + v11 * wx;
  out[idx] = top * (1.f - wy) + bot * wy;
}

extern "C" void kernel_launch(void* const* d_in, const int* in_sizes, int n_in,
                              void* d_out, int out_size, void* d_ws, size_t ws_size,
                              hipStream_t stream) {
  const float* feats = (const float*)d_in[0];
  const float* nfeats = (const float*)d_in[1];
  float* out = (float*)d_out;

  char* ws = (char*)d_ws;
  const size_t FQ_BYTES = (size_t)N1 * PP * DD;  // 6,291,456
  char* fq = ws;
  char* gq = ws + FQ_BYTES;
  int* rowmaxI = (int*)(ws + 2 * FQ_BYTES);
  float* sp = (float*)(ws + 2 * FQ_BYTES + (size_t)N1 * N2 * PP * 4);

  // No memset needed: every rowmaxI row is written exactly once by its
  // unique (pair, band) block.

  nrm_kernel<<<(N1 + N2) * PP, 256, 0, stream>>>(feats, nfeats, fq, gq);

  grami8_kernel<<<512, 512, 0, stream>>>(fq, gq, rowmaxI);

  finalize_kernel<<<N1, 256, 0, stream>>>(rowmaxI, sp, out);
  resize_kernel<<<(N1 * OH * OW) / 256, 256, 0, stream>>>(sp, out + 8);
}